// Round 7
// baseline (1970.566 us; speedup 1.0000x reference)
//
#include <hip/hip_runtime.h>
#include <hip/hip_bf16.h>
#include <math.h>

typedef __hip_bfloat16 bf16;
typedef __attribute__((ext_vector_type(4))) float floatx4;
typedef __attribute__((ext_vector_type(8))) short shortx8;

#define T_TOK 1154
#define C_DIM 768
#define H_HEADS 12
#define NLOC 577
#define OUT_PER 1769472  // 2*576*1536

// per-layer weight element counts (row-major [O,K])
#define NQ  1769472ull   // 2304*768
#define NP  589824ull    // 768*768
#define NF1 2359296ull   // 3072*768
#define NF2 2359296ull   // 768*3072
#define NWTOT 7077888ull // NQ+NP+NF1+NF2
// offsets into per-layer bf16 weight buffer
#define WQ  0ull
#define WP  1769472ull
#define WF1 2359296ull
#define WF2 4718592ull

static __device__ __forceinline__ float b2f(bf16 v) { return __bfloat162float(v); }
static __device__ __forceinline__ bf16 f2b(float v) { return __float2bfloat16(v); }

// async global->LDS, 16B per lane; LDS dest = wave-uniform base + lane*16 (linear)
static __device__ __forceinline__ void gload16(const bf16* g, short* l) {
    __builtin_amdgcn_global_load_lds(
        (__attribute__((address_space(1))) void*)(void*)g,
        (__attribute__((address_space(3))) void*)(void*)l, 16, 0, 0);
}

// ---------------- init: x (f32) -> f32 residual, camera token splice ----------------
__global__ void k_init(const float* __restrict__ xin, const float* __restrict__ cam,
                       float* __restrict__ xF, int total) {
    int idx = blockIdx.x * 256 + threadIdx.x;
    if (idx >= total) return;
    int t = idx / C_DIM, c = idx - t * C_DIM;
    int s = t / NLOC, n = t - s * NLOC;
    float v = (n == 0) ? cam[s * C_DIM + c] : xin[idx];
    xF[idx] = v;
}

// ---------------- cast f32 residual -> bf16 snapshot ----------------
__global__ void k_cast(const float* __restrict__ src, bf16* __restrict__ dst, int total) {
    int idx = blockIdx.x * 256 + threadIdx.x;
    if (idx < total) dst[idx] = f2b(src[idx]);
}

// ---------------- weight convert: f32 -> bf16, 3D grid, no division ----------------
__global__ __launch_bounds__(256) void k_wconv3(
    const float* __restrict__ wq, const float* __restrict__ wp,
    const float* __restrict__ wf1, const float* __restrict__ wf2,
    bf16* __restrict__ dst) {
    int typ = blockIdx.y, layer = blockIdx.z;
    size_t cnt, off;
    const float* srcb;
    if (typ == 0)      { cnt = NQ;  off = WQ;  srcb = wq; }
    else if (typ == 1) { cnt = NP;  off = WP;  srcb = wp; }
    else if (typ == 2) { cnt = NF1; off = WF1; srcb = wf1; }
    else               { cnt = NF2; off = WF2; srcb = wf2; }
    size_t e = ((size_t)blockIdx.x * 256 + threadIdx.x) * 8;
    if (e >= cnt) return;
    const float* src = srcb + (size_t)layer * cnt + e;
    bf16* d = dst + (size_t)layer * NWTOT + off + e;
    float4 a = *(const float4*)(src);
    float4 b = *(const float4*)(src + 4);
    bf16 pk[8];
    pk[0] = f2b(a.x); pk[1] = f2b(a.y); pk[2] = f2b(a.z); pk[3] = f2b(a.w);
    pk[4] = f2b(b.x); pk[5] = f2b(b.y); pk[6] = f2b(b.z); pk[7] = f2b(b.w);
    *(shortx8*)d = *(shortx8*)pk;
}

// ---------------- LayerNorm: f32 residual -> bf16 ----------------
__global__ __launch_bounds__(256) void k_ln(const float* __restrict__ xF,
                                            const float* __restrict__ w, const float* __restrict__ b,
                                            bf16* __restrict__ out) {
    int t = blockIdx.x;
    const float* xr = xF + (size_t)t * C_DIM;
    float s = 0.f, s2 = 0.f;
    for (int c = threadIdx.x; c < C_DIM; c += 256) { float v = xr[c]; s += v; s2 += v * v; }
    __shared__ float red[8];
    for (int o = 32; o; o >>= 1) { s += __shfl_xor(s, o, 64); s2 += __shfl_xor(s2, o, 64); }
    int wv = threadIdx.x >> 6;
    if ((threadIdx.x & 63) == 0) { red[wv] = s; red[4 + wv] = s2; }
    __syncthreads();
    s = red[0] + red[1] + red[2] + red[3];
    s2 = red[4] + red[5] + red[6] + red[7];
    float mean = s * (1.0f / C_DIM);
    float var = s2 * (1.0f / C_DIM) - mean * mean;
    if (var < 0.f) var = 0.f;
    float inv = rsqrtf(var + 1e-6f);
    bf16* orow = out + (size_t)t * C_DIM;
    for (int c = threadIdx.x; c < C_DIM; c += 256) {
        float v = (xr[c] - mean) * inv * w[c] + b[c];
        orow[c] = f2b(v);
    }
}

// ---------------- GEMM: out[M,N] = A[M,K](bf16) x Bt[N,K](bf16)^T ----------------
// BMxBN tile, BK=64, global_load_lds staging (linear LDS), double-buffered,
// ONE barrier per K-step. XOR chunk-swizzle involution both sides.
// MODE 1: outB = gelu_exact(acc + bias)   MODE 2: xio += gamma*(acc + bias)
// MODE 3: outB = acc + bias
template<int BM, int BN, int MODE>
__global__ __launch_bounds__(256) void k_gemmT(
    const bf16* __restrict__ A, const bf16* __restrict__ Bt,
    const float* __restrict__ bias, const float* __restrict__ gamma,
    bf16* __restrict__ outB, float* __restrict__ xio,
    int M, int N, int K, int mB, int kS) {
    constexpr int FM = BM / 32;
    constexpr int FN = BN / 32;
    __shared__ short At[2][BM * 64];
    __shared__ short Bs[2][BN * 64];
    int nwg = gridDim.x;
    int lid = blockIdx.x;
    int qd = nwg >> 3, rm = nwg & 7;
    int xcd = lid & 7, pos = lid >> 3;
    int lid2 = (xcd < rm ? xcd * (qd + 1) : rm * (qd + 1) + (xcd - rm) * qd) + pos;
    int mI = lid2 % mB;
    int rest = lid2 / mB;
    int nB = N / BN;
    int nI = rest % nB;
    int kI = rest / nB;
    int m0 = mI * BM, n0 = nI * BN;
    int Ksub = K / kS;
    int kOff = kI * Ksub;
    int tid = threadIdx.x;
    int w = tid >> 6, lane = tid & 63;
    int lr = lane & 15, lq = lane >> 4;
    int wm = w & 1, wn = w >> 1;
    int srow = tid >> 3;     // 0..31: row within a 32-row staging group
    int schk = tid & 7;      // 16B chunk (8 shorts) within 128B row
    floatx4 acc[FM][FN] = {};

    auto stage = [&](int buf, int k0) {
        #pragma unroll
        for (int j = 0; j < BM / 32; j++) {
            int r = j * 32 + srow;
            int ar = m0 + r; if (ar >= M) ar = M - 1;
            int gs = schk ^ (r & 7);
            gload16(A + (size_t)ar * K + kOff + k0 + gs * 8, &At[buf][r * 64 + schk * 8]);
        }
        #pragma unroll
        for (int j = 0; j < BN / 32; j++) {
            int r = j * 32 + srow;
            int gs = schk ^ (r & 7);
            gload16(Bt + (size_t)(n0 + r) * K + kOff + k0 + gs * 8, &Bs[buf][r * 64 + schk * 8]);
        }
    };

    int nt = Ksub / 64;
    stage(0, 0);
    __syncthreads();
    int cur = 0;
    int rx = lr & 7;
    for (int t = 0; t < nt; ++t) {
        if (t + 1 < nt) stage(cur ^ 1, (t + 1) * 64);
        #pragma unroll
        for (int kk = 0; kk < 2; kk++) {
            shortx8 af[FM], bg[FN];
            #pragma unroll
            for (int mi = 0; mi < FM; mi++) {
                int rowl = wm * (BM / 2) + mi * 16 + lr;
                af[mi] = *(const shortx8*)&At[cur][rowl * 64 + ((kk * 4 + lq) ^ rx) * 8];
            }
            #pragma unroll
            for (int ni = 0; ni < FN; ni++) {
                int rowl = wn * (BN / 2) + ni * 16 + lr;
                bg[ni] = *(const shortx8*)&Bs[cur][rowl * 64 + ((kk * 4 + lq) ^ rx) * 8];
            }
            #pragma unroll
            for (int mi = 0; mi < FM; mi++)
                #pragma unroll
                for (int ni = 0; ni < FN; ni++)
                    acc[mi][ni] = __builtin_amdgcn_mfma_f32_16x16x32_bf16(af[mi], bg[ni], acc[mi][ni], 0, 0, 0);
        }
        __syncthreads();
        cur ^= 1;
    }

    #pragma unroll
    for (int mi = 0; mi < FM; mi++) {
        #pragma unroll
        for (int ni = 0; ni < FN; ni++) {
            int cc = n0 + wn * (BN / 2) + ni * 16 + lr;
            #pragma unroll
            for (int rg = 0; rg < 4; rg++) {
                int rr = m0 + wm * (BM / 2) + mi * 16 + lq * 4 + rg;
                if (rr < M) {
                    float u = acc[mi][ni][rg];
                    if (MODE == 2) {
                        u += (kI == 0) ? bias[cc] : 0.f;
                        float contrib = gamma[cc] * u;
                        if (kS > 1) atomicAdd(&xio[(size_t)rr * N + cc], contrib);
                        else        xio[(size_t)rr * N + cc] += contrib;
                    } else if (MODE == 1) {
                        u += bias[cc];
                        float g = 0.5f * u * (1.0f + erff(u * 0.70710678118f));
                        outB[(size_t)rr * N + cc] = f2b(g);
                    } else {
                        u += bias[cc];
                        outB[(size_t)rr * N + cc] = f2b(u);
                    }
                }
            }
        }
    }
}

// ---------------- QKV GEMM (128x64 tile) + fused rms-norm + RoPE + head split ----
// Each 64-col tile is exactly one (head, {q|k|v}) chunk. Epilogue: v ->
// passthrough; q/k -> RMS (cross-wave via LDS) + RoPE (pair d^16 register-local,
// flips ni bit). Writes head-major.
__global__ __launch_bounds__(256) void k_gemmQKV(
    const bf16* __restrict__ A, const bf16* __restrict__ Bt,
    const float* __restrict__ bias,
    const float* __restrict__ qnw, const float* __restrict__ knw,
    const float* __restrict__ ctab, const float* __restrict__ stab, int posMod,
    bf16* __restrict__ qh, bf16* __restrict__ kh, bf16* __restrict__ vh,
    int M, int K) {
    constexpr int BM = 128, BN = 64, FM = 4, FN = 2;
    const int mB = 10;
    __shared__ short At[2][BM * 64];
    __shared__ short Bs[2][BN * 64];
    __shared__ float ssqS[2][BM];
    int nwg = gridDim.x;
    int lid = blockIdx.x;
    int qd = nwg >> 3, rm = nwg & 7;
    int xcd = lid & 7, pos = lid >> 3;
    int lid2 = (xcd < rm ? xcd * (qd + 1) : rm * (qd + 1) + (xcd - rm) * qd) + pos;
    int mI = lid2 % mB;
    int nI = lid2 / mB;
    int m0 = mI * BM, n0 = nI * BN;
    int tid = threadIdx.x;
    int w = tid >> 6, lane = tid & 63;
    int lr = lane & 15, lq = lane >> 4;
    int wm = w & 1, wn = w >> 1;
    int srow = tid >> 3, schk = tid & 7;
    floatx4 acc[FM][FN] = {};

    auto stage = [&](int buf, int k0) {
        #pragma unroll
        for (int j = 0; j < BM / 32; j++) {
            int r = j * 32 + srow;
            int ar = m0 + r; if (ar >= M) ar = M - 1;
            int gs = schk ^ (r & 7);
            gload16(A + (size_t)ar * K + k0 + gs * 8, &At[buf][r * 64 + schk * 8]);
        }
        #pragma unroll
        for (int j = 0; j < BN / 32; j++) {
            int r = j * 32 + srow;
            int gs = schk ^ (r & 7);
            gload16(Bt + (size_t)(n0 + r) * K + k0 + gs * 8, &Bs[buf][r * 64 + schk * 8]);
        }
    };

    int nt = K / 64;
    stage(0, 0);
    __syncthreads();
    int cur = 0;
    int rx = lr & 7;
    for (int t = 0; t < nt; ++t) {
        if (t + 1 < nt) stage(cur ^ 1, (t + 1) * 64);
        #pragma unroll
        for (int kk = 0; kk < 2; kk++) {
            shortx8 af[FM], bg[FN];
            #pragma unroll
            for (int mi = 0; mi < FM; mi++) {
                int rowl = wm * 64 + mi * 16 + lr;
                af[mi] = *(const shortx8*)&At[cur][rowl * 64 + ((kk * 4 + lq) ^ rx) * 8];
            }
            #pragma unroll
            for (int ni = 0; ni < FN; ni++) {
                int rowl = wn * 32 + ni * 16 + lr;
                bg[ni] = *(const shortx8*)&Bs[cur][rowl * 64 + ((kk * 4 + lq) ^ rx) * 8];
            }
            #pragma unroll
            for (int mi = 0; mi < FM; mi++)
                #pragma unroll
                for (int ni = 0; ni < FN; ni++)
                    acc[mi][ni] = __builtin_amdgcn_mfma_f32_16x16x32_bf16(af[mi], bg[ni], acc[mi][ni], 0, 0, 0);
        }
        __syncthreads();
        cur ^= 1;
    }

    // ---- fused epilogue ----
    int tile6 = n0 >> 6;              // 0..35
    int typ = tile6 / 12;             // 0=q, 1=k, 2=v
    int hh = tile6 - typ * 12;        // head
    float u[FM][FN][4];
    #pragma unroll
    for (int mi = 0; mi < FM; mi++)
        #pragma unroll
        for (int ni = 0; ni < FN; ni++) {
            int cc = n0 + wn * 32 + ni * 16 + lr;
            #pragma unroll
            for (int rg = 0; rg < 4; rg++) u[mi][ni][rg] = acc[mi][ni][rg] + bias[cc];
        }

    if (typ == 2) {
        // v: passthrough to head-major
        #pragma unroll
        for (int mi = 0; mi < FM; mi++)
            #pragma unroll
            for (int rg = 0; rg < 4; rg++) {
                int rr = m0 + wm * 64 + mi * 16 + lq * 4 + rg;
                if (rr < M) {
                    #pragma unroll
                    for (int ni = 0; ni < FN; ni++) {
                        int d = wn * 32 + ni * 16 + lr;
                        vh[((size_t)hh * T_TOK + rr) * 64 + d] = f2b(u[mi][ni][rg]);
                    }
                }
            }
        return;
    }

    // q/k: RMS norm over 64 dims (cols split across wn waves -> LDS exchange)
    float sq[FM][4];
    #pragma unroll
    for (int mi = 0; mi < FM; mi++)
        #pragma unroll
        for (int rg = 0; rg < 4; rg++) {
            float s = u[mi][0][rg] * u[mi][0][rg] + u[mi][1][rg] * u[mi][1][rg];
            for (int o = 1; o < 16; o <<= 1) s += __shfl_xor(s, o, 16);
            sq[mi][rg] = s;
        }
    if (lr == 0) {
        #pragma unroll
        for (int mi = 0; mi < FM; mi++)
            #pragma unroll
            for (int rg = 0; rg < 4; rg++)
                ssqS[wn][wm * 64 + mi * 16 + lq * 4 + rg] = sq[mi][rg];
    }
    __syncthreads();
    const float* wt = (typ == 0) ? qnw : knw;
    bf16* dstp = (typ == 0) ? qh : kh;
    int d0 = wn * 32 + lr;        // bit4 = 0 -> rot sign -
    int d1 = d0 + 16;             // bit4 = 1 -> rot sign +
    float w0 = wt[d0], w1 = wt[d1];
    #pragma unroll
    for (int mi = 0; mi < FM; mi++) {
        #pragma unroll
        for (int rg = 0; rg < 4; rg++) {
            int rowl = wm * 64 + mi * 16 + lq * 4 + rg;
            int rr = m0 + rowl;
            if (rr >= M) continue;
            float ssq = ssqS[0][rowl] + ssqS[1][rowl];
            float rinv = rsqrtf(ssq * (1.0f / 64.0f) + 1e-6f);
            float n0v = u[mi][0][rg] * rinv * w0;
            float n1v = u[mi][1][rg] * rinv * w1;
            int p = (rr >= posMod) ? rr - posMod : rr;   // rr < 2*posMod always
            float c0 = ctab[p * 64 + d0], s0 = stab[p * 64 + d0];
            float c1 = ctab[p * 64 + d1], s1 = stab[p * 64 + d1];
            float o0 = n0v * c0 - n1v * s0;
            float o1 = n1v * c1 + n0v * s1;
            size_t ob = ((size_t)hh * T_TOK + rr) * 64;
            dstp[ob + d0] = f2b(o0);
            dstp[ob + d1] = f2b(o1);
        }
    }
}

// ---------------- attention: flash-style MFMA, prefetched staging ----------------
__global__ __launch_bounds__(256) void k_attn2(
    const bf16* __restrict__ qh, const bf16* __restrict__ kh, const bf16* __restrict__ vh,
    const float* __restrict__ mask, bf16* __restrict__ out, int nk) {
    __shared__ short Ks[64 * 72];
    __shared__ short Vs[64 * 72];      // V^T tile: [d][k]
    __shared__ short Ps[4][16 * 72];   // per-wave P (bf16)
    __shared__ float bias_s[64];
    int h = blockIdx.y;
    int base = blockIdx.z * nk;
    int tid = threadIdx.x;
    int wv = tid >> 6, lane = tid & 63;
    int lr = lane & 15, lq = lane >> 4;
    int q0 = blockIdx.x * 64 + wv * 16;
    shortx8 qf[2];
    {
        int qr = q0 + lr; if (qr >= nk) qr = nk - 1;
        const bf16* qp = qh + ((size_t)h * T_TOK + base + qr) * 64 + lq * 8;
        qf[0] = *(const shortx8*)(qp);
        qf[1] = *(const shortx8*)(qp + 32);
    }
    int kKr[2], kSeg[2], vKr[2], vSeg[2];
    #pragma unroll
    for (int c = 0; c < 2; c++) {
        int idx = tid + c * 256;
        kKr[c] = idx >> 3; kSeg[c] = idx & 7;
        vKr[c] = idx & 63; vSeg[c] = idx >> 6;
    }
    shortx8 kpre[2], vpre[2];
    float bpre = 0.f;
    auto prefetch = [&](int kbase) {
        #pragma unroll
        for (int c = 0; c < 2; c++) {
            int gk = kbase + kKr[c];
            shortx8 kv = {};
            if (gk < nk) kv = *(const shortx8*)(kh + ((size_t)h * T_TOK + base + gk) * 64 + kSeg[c] * 8);
            kpre[c] = kv;
            int gv = kbase + vKr[c];
            shortx8 vv = {};
            if (gv < nk) vv = *(const shortx8*)(vh + ((size_t)h * T_TOK + base + gv) * 64 + vSeg[c] * 8);
            vpre[c] = vv;
        }
        if (tid < 64) {
            int gk = kbase + tid;
            bpre = (gk < nk) ? (1.0f - mask[base + gk]) * -10000.0f : -30000.0f;
        }
    };
    float mrow[4] = {-3.0e38f, -3.0e38f, -3.0e38f, -3.0e38f};
    float lrow[4] = {0.f, 0.f, 0.f, 0.f};
    floatx4 accO[4] = {};
    short* pbuf = &Ps[wv][0];
    int nkt = (nk + 63) >> 6;
    prefetch(0);
    for (int kt0 = 0; kt0 < nkt; kt0++) {
        __syncthreads();
        #pragma unroll
        for (int c = 0; c < 2; c++) {
            *(shortx8*)&Ks[kKr[c] * 72 + kSeg[c] * 8] = kpre[c];
            bf16* vb = (bf16*)&vpre[c];
            #pragma unroll
            for (int j = 0; j < 8; j++)
                Vs[(vSeg[c] * 8 + j) * 72 + vKr[c]] = *(short*)&vb[j];
        }
        if (tid < 64) bias_s[tid] = bpre;
        if (kt0 + 1 < nkt) prefetch((kt0 + 1) * 64);
        __syncthreads();
        floatx4 s[4];
        #pragma unroll
        for (int nt = 0; nt < 4; nt++) {
            floatx4 accS = {};
            shortx8 k0 = *(const shortx8*)&Ks[(nt * 16 + lr) * 72 + lq * 8];
            shortx8 k1 = *(const shortx8*)&Ks[(nt * 16 + lr) * 72 + 32 + lq * 8];
            accS = __builtin_amdgcn_mfma_f32_16x16x32_bf16(qf[0], k0, accS, 0, 0, 0);
            accS = __builtin_amdgcn_mfma_f32_16x16x32_bf16(qf[1], k1, accS, 0, 0, 0);
            s[nt] = accS;
        }
        float tmax[4] = {-3.0e38f, -3.0e38f, -3.0e38f, -3.0e38f};
        #pragma unroll
        for (int nt = 0; nt < 4; nt++) {
            float bv = bias_s[nt * 16 + lr];
            #pragma unroll
            for (int rg = 0; rg < 4; rg++) {
                float sv = s[nt][rg] * 0.125f + bv;
                s[nt][rg] = sv;
                tmax[rg] = fmaxf(tmax[rg], sv);
            }
        }
        #pragma unroll
        for (int rg = 0; rg < 4; rg++) {
            for (int o = 1; o < 16; o <<= 1) tmax[rg] = fmaxf(tmax[rg], __shfl_xor(tmax[rg], o, 16));
        }
        float fac[4], tsum[4] = {0.f, 0.f, 0.f, 0.f};
        #pragma unroll
        for (int rg = 0; rg < 4; rg++) {
            float mn = fmaxf(mrow[rg], tmax[rg]);
            fac[rg] = __expf(mrow[rg] - mn);
            mrow[rg] = mn;
        }
        #pragma unroll
        for (int nt = 0; nt < 4; nt++) {
            #pragma unroll
            for (int rg = 0; rg < 4; rg++) {
                float e = __expf(s[nt][rg] - mrow[rg]);
                s[nt][rg] = e;
                tsum[rg] += e;
            }
        }
        #pragma unroll
        for (int rg = 0; rg < 4; rg++) {
            for (int o = 1; o < 16; o <<= 1) tsum[rg] += __shfl_xor(tsum[rg], o, 16);
            lrow[rg] = lrow[rg] * fac[rg] + tsum[rg];
        }
        #pragma unroll
        for (int dt = 0; dt < 4; dt++)
            #pragma unroll
            for (int rg = 0; rg < 4; rg++) accO[dt][rg] *= fac[rg];
        #pragma unroll
        for (int nt = 0; nt < 4; nt++) {
            #pragma unroll
            for (int rg = 0; rg < 4; rg++) {
                bf16 pv = f2b(s[nt][rg]);
                pbuf[(lq * 4 + rg) * 72 + nt * 16 + lr] = *(short*)&pv;
            }
        }
        #pragma unroll
        for (int ks = 0; ks < 2; ks++) {
            shortx8 pf = *(const shortx8*)&pbuf[lr * 72 + ks * 32 + lq * 8];
            #pragma unroll
            for (int dt = 0; dt < 4; dt++) {
                shortx8 vf = *(const shortx8*)&Vs[(dt * 16 + lr) * 72 + ks * 32 + lq * 8];
                accO[dt] = __builtin_amdgcn_mfma_f32_16x16x32_bf16(pf, vf, accO[dt], 0, 0, 0);
            }
        }
    }
    float invl[4];
    #pragma unroll
    for (int rg = 0; rg < 4; rg++) invl[rg] = 1.0f / lrow[rg];
    #pragma unroll
    for (int rg = 0; rg < 4; rg++) {
        int qr = q0 + lq * 4 + rg;
        if (qr < nk) {
            bf16* orow = out + (size_t)(base + qr) * C_DIM + h * 64 + lr;
            #pragma unroll
            for (int dt = 0; dt < 4; dt++)
                orow[dt * 16] = f2b(accO[dt][rg] * invl[rg]);
        }
    }
}

// ---------------- output assembly at OUT layers (f32 out) ----------------
__global__ __launch_bounds__(256) void k_output(
    const float* __restrict__ xF, const bf16* __restrict__ lxB,
    const float* __restrict__ fw, const float* __restrict__ fb, float* __restrict__ dst) {
    int b = blockIdx.x;                 // 0..1151
    int s = b / 576, nn = b - s * 576;
    int t = s * NLOC + nn + 1;          // skip token 0
    const float* xr = xF + (size_t)t * C_DIM;
    float sum = 0.f, s2 = 0.f;
    for (int c = threadIdx.x; c < C_DIM; c += 256) { float v = xr[c]; sum += v; s2 += v * v; }
    __shared__ float red[8];
    for (int o = 32; o; o >>= 1) { sum += __shfl_xor(sum, o, 64); s2 += __shfl_xor(s2, o, 64); }
    if ((threadIdx.x & 63) == 0) { red[threadIdx.x >> 6] = sum; red[4 + (threadIdx.x >> 6)] = s2; }
    __syncthreads();
    sum = red[0] + red[1] + red[2] + red[3];
    s2 = red[4] + red[5] + red[6] + red[7];
    float mean = sum * (1.0f / C_DIM);
    float var = s2 * (1.0f / C_DIM) - mean * mean;
    if (var < 0.f) var = 0.f;
    float inv = rsqrtf(var + 1e-6f);
    float* orow = dst + (size_t)b * 1536;
    const bf16* lr = lxB + (size_t)t * C_DIM;
    for (int c = threadIdx.x; c < C_DIM; c += 256) {
        orow[c] = b2f(lr[c]);
        float v = (xr[c] - mean) * inv * fw[c] + fb[c];
        orow[768 + c] = v;
    }
}

// ---------------- camera tokens (layer 11, no final LN) ----------------
__global__ void k_cam(const float* __restrict__ xF, const bf16* __restrict__ lxB,
                      float* __restrict__ dst) {
    for (int idx = threadIdx.x; idx < 2 * 1536; idx += 256) {
        int s = idx / 1536, c = idx - s * 1536;
        int t = s * NLOC;
        float v = (c < 768) ? b2f(lxB[(size_t)t * 768 + c]) : xF[(size_t)t * 768 + (c - 768)];
        dst[idx] = v;
    }
}

extern "C" void kernel_launch(void* const* d_in, const int* in_sizes, int n_in,
                              void* d_out, int out_size, void* d_ws, size_t ws_size,
                              hipStream_t stream) {
    const float* xin  = (const float*)d_in[0];
    const float* rcl  = (const float*)d_in[1];
    const float* rsl  = (const float*)d_in[2];
    const float* rcg  = (const float*)d_in[3];
    const float* rsg  = (const float*)d_in[4];
    const float* kvl  = (const float*)d_in[5];
    const float* kvg  = (const float*)d_in[6];
    const float* cam  = (const float*)d_in[7];
    const float* qkvw = (const float*)d_in[8];
    const float* qkvb = (const float*)d_in[9];
    const float* qnw  = (const float*)d_in[10];
    const float* knw  = (const float*)d_in[11];
    const float* pw   = (const float*)d_in[12];
    const float* pb   = (const float*)d_in[13];
    const float* ls1  = (const float*)d_in[14];
    const float* ls2  = (const float*)d_in[15];
    const float* n1w  = (const float*)d_in[16];
    const float* n1b  = (const float*)d_in[17];
    const float* n2w  = (const float*)d_in[18];
    const float* n2b  = (const float*)d_in[19];
    const float* f1w  = (const float*)d_in[20];
    const float* f1b  = (const float*)d_in[21];
    const float* f2w  = (const float*)d_in[22];
    const float* f2b_ = (const float*)d_in[23];
    const float* fnw  = (const float*)d_in[24];
    const float* fnb  = (const float*)d_in[25];

    char* ws = (char*)d_ws;
    const size_t TC = (size_t)T_TOK * C_DIM;                 // 886,272
    float* xF  = (float*)ws; ws += TC * 4;
    bf16* bufA = (bf16*)ws;  ws += (size_t)T_TOK * 3072 * 2;
    bf16* qhb  = (bf16*)ws;  ws += TC * 2;
    bf16* khb  = (bf16*)ws;  ws += TC * 2;
    bf16* vhb  = (bf16*)ws;  ws += TC * 2;
    bf16* hbuf = (bf16*)ws;  ws += TC * 2;
    bf16* lxB  = (bf16*)ws;  ws += TC * 2;
    bf16* wAll = (bf16*)ws;
    size_t usedBase = (size_t)(ws - (char*)d_ws);
    bool bigW = ws_size >= usedBase + 12ull * NWTOT * 2ull;  // 170 MB for all-layer weights
    (void)n_in; (void)in_sizes; (void)out_size;

    float* out_b = (float*)d_out;

    k_init<<<(int)((TC + 255) / 256), 256, 0, stream>>>(xin, cam, xF, (int)TC);
    if (bigW)
        k_wconv3<<<dim3(1152, 4, 12), 256, 0, stream>>>(qkvw, pw, f1w, f2w, wAll);

    int outIdx = 0;
    for (int i = 0; i < 12; i++) {
        bool isGlobal = (i & 1);
        bf16* wL;
        if (bigW) {
            wL = wAll + (size_t)i * NWTOT;
        } else {
            k_wconv3<<<dim3(1152, 4, 1), 256, 0, stream>>>(
                qkvw + (size_t)i * NQ, pw + (size_t)i * NP,
                f1w + (size_t)i * NF1, f2w + (size_t)i * NF2, wAll);
            wL = wAll;
        }
        // LN1
        k_ln<<<T_TOK, 256, 0, stream>>>(xF, n1w + (size_t)i * 768, n1b + (size_t)i * 768, hbuf);
        // QKV gemm (128x64) + fused rms/rope/split -> qhb/khb/vhb, grid 10*36=360
        k_gemmQKV<<<360, 256, 0, stream>>>(hbuf, wL + WQ,
            qkvb + (size_t)i * 2304,
            qnw + (size_t)i * 64, knw + (size_t)i * 64,
            isGlobal ? rcg : rcl, isGlobal ? rsg : rsl, isGlobal ? 1154 : 577,
            qhb, khb, vhb, T_TOK, 768);
        // attention -> hbuf
        if (isGlobal)
            k_attn2<<<dim3(19, 12, 1), 256, 0, stream>>>(qhb, khb, vhb, kvg, hbuf, 1154);
        else
            k_attn2<<<dim3(10, 12, 2), 256, 0, stream>>>(qhb, khb, vhb, kvl, hbuf, 577);
        // proj + residual: 64x64, split-K x2 (atomic), grid 19*12*2=456
        k_gemmT<64, 64, 2><<<456, 256, 0, stream>>>(hbuf, wL + WP,
            pb + (size_t)i * 768, ls1 + (size_t)i * 768, nullptr, xF, T_TOK, 768, 768, 19, 2);
        // LN2
        k_ln<<<T_TOK, 256, 0, stream>>>(xF, n2w + (size_t)i * 768, n2b + (size_t)i * 768, hbuf);
        // fc1 + gelu -> bufA: 128x64, grid 10*48=480
        k_gemmT<128, 64, 1><<<480, 256, 0, stream>>>(hbuf, wL + WF1,
            f1b + (size_t)i * 3072, nullptr, bufA, nullptr, T_TOK, 3072, 768, 10, 1);
        // fc2 + residual: 128x64, split-K x3 (atomic), grid 10*12*3=360
        k_gemmT<128, 64, 2><<<360, 256, 0, stream>>>(bufA, wL + WF2,
            f2b_ + (size_t)i * 768, ls2 + (size_t)i * 768, nullptr, xF, T_TOK, 768, 3072, 10, 3);

        // snapshot local_x
        if (i == 2 || i == 4 || i == 8 || i == 10)
            k_cast<<<(int)((TC + 255) / 256), 256, 0, stream>>>(xF, lxB, (int)TC);

        if (i == 2 || i == 5 || i == 8 || i == 11) {
            k_output<<<1152, 256, 0, stream>>>(xF, lxB, fnw, fnb, out_b + (size_t)outIdx * OUT_PER);
            if (i == 11)
                k_cam<<<1, 256, 0, stream>>>(xF, lxB, out_b + 4ull * OUT_PER);
            outIdx++;
        }
    }
}

// Round 8
// 1775.094 us; speedup vs baseline: 1.1101x; 1.1101x over previous
//
#include <hip/hip_runtime.h>
#include <hip/hip_bf16.h>
#include <math.h>

typedef __hip_bfloat16 bf16;
typedef __attribute__((ext_vector_type(4))) float floatx4;
typedef __attribute__((ext_vector_type(8))) short shortx8;

#define T_TOK 1154
#define C_DIM 768
#define H_HEADS 12
#define NLOC 577
#define OUT_PER 1769472  // 2*576*1536

// per-layer weight element counts (row-major [O,K])
#define NQ  1769472ull   // 2304*768
#define NP  589824ull    // 768*768
#define NF1 2359296ull   // 3072*768
#define NF2 2359296ull   // 768*3072
#define NWTOT 7077888ull // NQ+NP+NF1+NF2
// offsets into per-layer bf16 weight buffer
#define WQ  0ull
#define WP  1769472ull
#define WF1 2359296ull
#define WF2 4718592ull

static __device__ __forceinline__ float b2f(bf16 v) { return __bfloat162float(v); }
static __device__ __forceinline__ bf16 f2b(float v) { return __float2bfloat16(v); }

// async global->LDS, 16B per lane; LDS dest = wave-uniform base + lane*16 (linear)
static __device__ __forceinline__ void gload16(const bf16* g, short* l) {
    __builtin_amdgcn_global_load_lds(
        (__attribute__((address_space(1))) void*)(void*)g,
        (__attribute__((address_space(3))) void*)(void*)l, 16, 0, 0);
}

// ---------------- init: x (f32) -> f32 residual, camera token splice ----------------
__global__ void k_init(const float* __restrict__ xin, const float* __restrict__ cam,
                       float* __restrict__ xF, int total) {
    int idx = blockIdx.x * 256 + threadIdx.x;
    if (idx >= total) return;
    int t = idx / C_DIM, c = idx - t * C_DIM;
    int s = t / NLOC, n = t - s * NLOC;
    float v = (n == 0) ? cam[s * C_DIM + c] : xin[idx];
    xF[idx] = v;
}

// ---------------- fold partials into xF (+ optional bf16 snapshot) ----------------
__global__ __launch_bounds__(256) void k_fold(
    float* __restrict__ xF, const float* __restrict__ p0, const float* __restrict__ p1,
    bf16* __restrict__ lxB, int doCast, int total4) {
    int i = blockIdx.x * 256 + threadIdx.x;
    if (i >= total4) return;
    float4 x = ((float4*)xF)[i];
    float4 a = ((const float4*)p0)[i];
    float4 b = ((const float4*)p1)[i];
    x.x += a.x + b.x; x.y += a.y + b.y; x.z += a.z + b.z; x.w += a.w + b.w;
    ((float4*)xF)[i] = x;
    if (doCast) {
        bf16 pk[4];
        pk[0] = f2b(x.x); pk[1] = f2b(x.y); pk[2] = f2b(x.z); pk[3] = f2b(x.w);
        *(short4*)(lxB + (size_t)i * 4) = *(short4*)pk;
    }
}

// ---------------- weight convert: f32 -> bf16, 3D grid, 16 elems/thread ----------
__global__ __launch_bounds__(256) void k_wconv3(
    const float* __restrict__ wq, const float* __restrict__ wp,
    const float* __restrict__ wf1, const float* __restrict__ wf2,
    bf16* __restrict__ dst) {
    int typ = blockIdx.y, layer = blockIdx.z;
    size_t cnt, off;
    const float* srcb;
    if (typ == 0)      { cnt = NQ;  off = WQ;  srcb = wq; }
    else if (typ == 1) { cnt = NP;  off = WP;  srcb = wp; }
    else if (typ == 2) { cnt = NF1; off = WF1; srcb = wf1; }
    else               { cnt = NF2; off = WF2; srcb = wf2; }
    size_t e = ((size_t)blockIdx.x * 256 + threadIdx.x) * 16;
    if (e >= cnt) return;
    const float* src = srcb + (size_t)layer * cnt + e;
    bf16* d = dst + (size_t)layer * NWTOT + off + e;
    #pragma unroll
    for (int h = 0; h < 2; h++) {
        float4 a = *(const float4*)(src + h * 8);
        float4 b = *(const float4*)(src + h * 8 + 4);
        bf16 pk[8];
        pk[0] = f2b(a.x); pk[1] = f2b(a.y); pk[2] = f2b(a.z); pk[3] = f2b(a.w);
        pk[4] = f2b(b.x); pk[5] = f2b(b.y); pk[6] = f2b(b.z); pk[7] = f2b(b.w);
        *(shortx8*)(d + h * 8) = *(shortx8*)pk;
    }
}

// ---------------- LayerNorm (optionally folding two f32 partials into xF) -------
__global__ __launch_bounds__(256) void k_ln(
    float* __restrict__ xF, const float* __restrict__ p0, const float* __restrict__ p1,
    const float* __restrict__ w, const float* __restrict__ b,
    bf16* __restrict__ out, int fold) {
    __shared__ float rowS[C_DIM];
    __shared__ float red[8];
    int t = blockIdx.x;
    float* xr = xF + (size_t)t * C_DIM;
    float s = 0.f, s2 = 0.f;
    for (int c = threadIdx.x; c < C_DIM; c += 256) {
        float v = xr[c];
        if (fold) {
            v += p0[(size_t)t * C_DIM + c] + p1[(size_t)t * C_DIM + c];
            xr[c] = v;
        }
        rowS[c] = v;
        s += v; s2 += v * v;
    }
    for (int o = 32; o; o >>= 1) { s += __shfl_xor(s, o, 64); s2 += __shfl_xor(s2, o, 64); }
    int wv = threadIdx.x >> 6;
    if ((threadIdx.x & 63) == 0) { red[wv] = s; red[4 + wv] = s2; }
    __syncthreads();
    s = red[0] + red[1] + red[2] + red[3];
    s2 = red[4] + red[5] + red[6] + red[7];
    float mean = s * (1.0f / C_DIM);
    float var = s2 * (1.0f / C_DIM) - mean * mean;
    if (var < 0.f) var = 0.f;
    float inv = rsqrtf(var + 1e-6f);
    bf16* orow = out + (size_t)t * C_DIM;
    for (int c = threadIdx.x; c < C_DIM; c += 256) {
        float v = (rowS[c] - mean) * inv * w[c] + b[c];
        orow[c] = f2b(v);
    }
}

// ---------------- GEMM: out[M,N] = A[M,K](bf16) x Bt[N,K](bf16)^T ----------------
// 64x64 tile, BK=64, global_load_lds staging (linear LDS), double-buffered,
// ONE barrier per K-step. XOR chunk-swizzle involution both sides.
// MODE 1: outB = gelu_exact(acc + bias)   MODE 3: outB = acc + bias
// MODE 4: partial[kI] = gamma*(acc + bias*(kI==0))   (plain stores, no atomics)
template<int BM, int BN, int MODE>
__global__ __launch_bounds__(256) void k_gemmT(
    const bf16* __restrict__ A, const bf16* __restrict__ Bt,
    const float* __restrict__ bias, const float* __restrict__ gamma,
    bf16* __restrict__ outB, float* __restrict__ xio,
    int M, int N, int K, int mB, int kS) {
    constexpr int FM = BM / 32;
    constexpr int FN = BN / 32;
    __shared__ short At[2][BM * 64];
    __shared__ short Bs[2][BN * 64];
    int nwg = gridDim.x;
    int lid = blockIdx.x;
    int qd = nwg >> 3, rm = nwg & 7;
    int xcd = lid & 7, pos = lid >> 3;
    int lid2 = (xcd < rm ? xcd * (qd + 1) : rm * (qd + 1) + (xcd - rm) * qd) + pos;
    int mI = lid2 % mB;
    int rest = lid2 / mB;
    int nB = N / BN;
    int nI = rest % nB;
    int kI = rest / nB;
    int m0 = mI * BM, n0 = nI * BN;
    int Ksub = K / kS;
    int kOff = kI * Ksub;
    int tid = threadIdx.x;
    int w = tid >> 6, lane = tid & 63;
    int lr = lane & 15, lq = lane >> 4;
    int wm = w & 1, wn = w >> 1;
    int srow = tid >> 3;     // 0..31: row within a 32-row staging group
    int schk = tid & 7;      // 16B chunk (8 shorts) within 128B row
    floatx4 acc[FM][FN] = {};

    auto stage = [&](int buf, int k0) {
        #pragma unroll
        for (int j = 0; j < BM / 32; j++) {
            int r = j * 32 + srow;
            int ar = m0 + r; if (ar >= M) ar = M - 1;
            int gs = schk ^ (r & 7);
            gload16(A + (size_t)ar * K + kOff + k0 + gs * 8, &At[buf][r * 64 + schk * 8]);
        }
        #pragma unroll
        for (int j = 0; j < BN / 32; j++) {
            int r = j * 32 + srow;
            int gs = schk ^ (r & 7);
            gload16(Bt + (size_t)(n0 + r) * K + kOff + k0 + gs * 8, &Bs[buf][r * 64 + schk * 8]);
        }
    };

    int nt = Ksub / 64;
    stage(0, 0);
    __syncthreads();
    int cur = 0;
    int rx = lr & 7;
    for (int t = 0; t < nt; ++t) {
        if (t + 1 < nt) stage(cur ^ 1, (t + 1) * 64);
        #pragma unroll
        for (int kk = 0; kk < 2; kk++) {
            shortx8 af[FM], bg[FN];
            #pragma unroll
            for (int mi = 0; mi < FM; mi++) {
                int rowl = wm * (BM / 2) + mi * 16 + lr;
                af[mi] = *(const shortx8*)&At[cur][rowl * 64 + ((kk * 4 + lq) ^ rx) * 8];
            }
            #pragma unroll
            for (int ni = 0; ni < FN; ni++) {
                int rowl = wn * (BN / 2) + ni * 16 + lr;
                bg[ni] = *(const shortx8*)&Bs[cur][rowl * 64 + ((kk * 4 + lq) ^ rx) * 8];
            }
            #pragma unroll
            for (int mi = 0; mi < FM; mi++)
                #pragma unroll
                for (int ni = 0; ni < FN; ni++)
                    acc[mi][ni] = __builtin_amdgcn_mfma_f32_16x16x32_bf16(af[mi], bg[ni], acc[mi][ni], 0, 0, 0);
        }
        __syncthreads();
        cur ^= 1;
    }

    #pragma unroll
    for (int mi = 0; mi < FM; mi++) {
        #pragma unroll
        for (int ni = 0; ni < FN; ni++) {
            int cc = n0 + wn * (BN / 2) + ni * 16 + lr;
            #pragma unroll
            for (int rg = 0; rg < 4; rg++) {
                int rr = m0 + wm * (BM / 2) + mi * 16 + lq * 4 + rg;
                if (rr < M) {
                    float u = acc[mi][ni][rg];
                    if (MODE == 4) {
                        u += (kI == 0) ? bias[cc] : 0.f;
                        xio[(size_t)kI * ((size_t)M * N) + (size_t)rr * N + cc] = gamma[cc] * u;
                    } else if (MODE == 1) {
                        u += bias[cc];
                        float g = 0.5f * u * (1.0f + erff(u * 0.70710678118f));
                        outB[(size_t)rr * N + cc] = f2b(g);
                    } else {
                        u += bias[cc];
                        outB[(size_t)rr * N + cc] = f2b(u);
                    }
                }
            }
        }
    }
}

// ---------------- QKV GEMM (64x64) + fused rms-norm + RoPE + head split ----------
__global__ __launch_bounds__(256) void k_gemmQKV(
    const bf16* __restrict__ A, const bf16* __restrict__ Bt,
    const float* __restrict__ bias,
    const float* __restrict__ qnw, const float* __restrict__ knw,
    const float* __restrict__ ctab, const float* __restrict__ stab, int posMod,
    bf16* __restrict__ qh, bf16* __restrict__ kh, bf16* __restrict__ vh,
    int M, int K) {
    constexpr int BM = 64, BN = 64, FM = 2, FN = 2;
    const int mB = 19;
    __shared__ short At[2][BM * 64];
    __shared__ short Bs[2][BN * 64];
    __shared__ float ssqS[2][64];
    int nwg = gridDim.x;
    int lid = blockIdx.x;
    int qd = nwg >> 3, rm = nwg & 7;
    int xcd = lid & 7, pos = lid >> 3;
    int lid2 = (xcd < rm ? xcd * (qd + 1) : rm * (qd + 1) + (xcd - rm) * qd) + pos;
    int mI = lid2 % mB;
    int nI = lid2 / mB;
    int m0 = mI * BM, n0 = nI * BN;
    int tid = threadIdx.x;
    int w = tid >> 6, lane = tid & 63;
    int lr = lane & 15, lq = lane >> 4;
    int wm = w & 1, wn = w >> 1;
    int srow = tid >> 3, schk = tid & 7;
    floatx4 acc[FM][FN] = {};

    auto stage = [&](int buf, int k0) {
        #pragma unroll
        for (int j = 0; j < BM / 32; j++) {
            int r = j * 32 + srow;
            int ar = m0 + r; if (ar >= M) ar = M - 1;
            int gs = schk ^ (r & 7);
            gload16(A + (size_t)ar * K + k0 + gs * 8, &At[buf][r * 64 + schk * 8]);
        }
        #pragma unroll
        for (int j = 0; j < BN / 32; j++) {
            int r = j * 32 + srow;
            int gs = schk ^ (r & 7);
            gload16(Bt + (size_t)(n0 + r) * K + k0 + gs * 8, &Bs[buf][r * 64 + schk * 8]);
        }
    };

    int nt = K / 64;
    stage(0, 0);
    __syncthreads();
    int cur = 0;
    int rx = lr & 7;
    for (int t = 0; t < nt; ++t) {
        if (t + 1 < nt) stage(cur ^ 1, (t + 1) * 64);
        #pragma unroll
        for (int kk = 0; kk < 2; kk++) {
            shortx8 af[FM], bg[FN];
            #pragma unroll
            for (int mi = 0; mi < FM; mi++) {
                int rowl = wm * 32 + mi * 16 + lr;
                af[mi] = *(const shortx8*)&At[cur][rowl * 64 + ((kk * 4 + lq) ^ rx) * 8];
            }
            #pragma unroll
            for (int ni = 0; ni < FN; ni++) {
                int rowl = wn * 32 + ni * 16 + lr;
                bg[ni] = *(const shortx8*)&Bs[cur][rowl * 64 + ((kk * 4 + lq) ^ rx) * 8];
            }
            #pragma unroll
            for (int mi = 0; mi < FM; mi++)
                #pragma unroll
                for (int ni = 0; ni < FN; ni++)
                    acc[mi][ni] = __builtin_amdgcn_mfma_f32_16x16x32_bf16(af[mi], bg[ni], acc[mi][ni], 0, 0, 0);
        }
        __syncthreads();
        cur ^= 1;
    }

    // ---- fused epilogue ----
    int tile6 = n0 >> 6;              // 0..35
    int typ = tile6 / 12;             // 0=q, 1=k, 2=v
    int hh = tile6 - typ * 12;        // head
    float u[FM][FN][4];
    #pragma unroll
    for (int mi = 0; mi < FM; mi++)
        #pragma unroll
        for (int ni = 0; ni < FN; ni++) {
            int cc = n0 + wn * 32 + ni * 16 + lr;
            #pragma unroll
            for (int rg = 0; rg < 4; rg++) u[mi][ni][rg] = acc[mi][ni][rg] + bias[cc];
        }

    if (typ == 2) {
        #pragma unroll
        for (int mi = 0; mi < FM; mi++)
            #pragma unroll
            for (int rg = 0; rg < 4; rg++) {
                int rr = m0 + wm * 32 + mi * 16 + lq * 4 + rg;
                if (rr < M) {
                    #pragma unroll
                    for (int ni = 0; ni < FN; ni++) {
                        int d = wn * 32 + ni * 16 + lr;
                        vh[((size_t)hh * T_TOK + rr) * 64 + d] = f2b(u[mi][ni][rg]);
                    }
                }
            }
        return;
    }

    // q/k: RMS norm over 64 dims (cols split across wn waves -> LDS exchange)
    float sq[FM][4];
    #pragma unroll
    for (int mi = 0; mi < FM; mi++)
        #pragma unroll
        for (int rg = 0; rg < 4; rg++) {
            float s = u[mi][0][rg] * u[mi][0][rg] + u[mi][1][rg] * u[mi][1][rg];
            for (int o = 1; o < 16; o <<= 1) s += __shfl_xor(s, o, 16);
            sq[mi][rg] = s;
        }
    if (lr == 0) {
        #pragma unroll
        for (int mi = 0; mi < FM; mi++)
            #pragma unroll
            for (int rg = 0; rg < 4; rg++)
                ssqS[wn][wm * 32 + mi * 16 + lq * 4 + rg] = sq[mi][rg];
    }
    __syncthreads();
    const float* wt = (typ == 0) ? qnw : knw;
    bf16* dstp = (typ == 0) ? qh : kh;
    int d0 = wn * 32 + lr;        // bit4 = 0 -> rot sign -
    int d1 = d0 + 16;             // bit4 = 1 -> rot sign +
    float w0 = wt[d0], w1 = wt[d1];
    #pragma unroll
    for (int mi = 0; mi < FM; mi++) {
        #pragma unroll
        for (int rg = 0; rg < 4; rg++) {
            int rowl = wm * 32 + mi * 16 + lq * 4 + rg;
            int rr = m0 + rowl;
            if (rr >= M) continue;
            float ssq = ssqS[0][rowl] + ssqS[1][rowl];
            float rinv = rsqrtf(ssq * (1.0f / 64.0f) + 1e-6f);
            float n0v = u[mi][0][rg] * rinv * w0;
            float n1v = u[mi][1][rg] * rinv * w1;
            int p = (rr >= posMod) ? rr - posMod : rr;   // rr < 2*posMod always
            float c0 = ctab[p * 64 + d0], s0 = stab[p * 64 + d0];
            float c1 = ctab[p * 64 + d1], s1 = stab[p * 64 + d1];
            float o0 = n0v * c0 - n1v * s0;
            float o1 = n1v * c1 + n0v * s1;
            size_t ob = ((size_t)hh * T_TOK + rr) * 64;
            dstp[ob + d0] = f2b(o0);
            dstp[ob + d1] = f2b(o1);
        }
    }
}

// ---------------- attention: flash-style MFMA, prefetched staging ----------------
__global__ __launch_bounds__(256) void k_attn2(
    const bf16* __restrict__ qh, const bf16* __restrict__ kh, const bf16* __restrict__ vh,
    const float* __restrict__ mask, bf16* __restrict__ out, int nk) {
    __shared__ short Ks[64 * 72];
    __shared__ short Vs[64 * 72];      // V^T tile: [d][k]
    __shared__ short Ps[4][16 * 72];   // per-wave P (bf16)
    __shared__ float bias_s[64];
    int h = blockIdx.y;
    int base = blockIdx.z * nk;
    int tid = threadIdx.x;
    int wv = tid >> 6, lane = tid & 63;
    int lr = lane & 15, lq = lane >> 4;
    int q0 = blockIdx.x * 64 + wv * 16;
    shortx8 qf[2];
    {
        int qr = q0 + lr; if (qr >= nk) qr = nk - 1;
        const bf16* qp = qh + ((size_t)h * T_TOK + base + qr) * 64 + lq * 8;
        qf[0] = *(const shortx8*)(qp);
        qf[1] = *(const shortx8*)(qp + 32);
    }
    int kKr[2], kSeg[2], vKr[2], vSeg[2];
    #pragma unroll
    for (int c = 0; c < 2; c++) {
        int idx = tid + c * 256;
        kKr[c] = idx >> 3; kSeg[c] = idx & 7;
        vKr[c] = idx & 63; vSeg[c] = idx >> 6;
    }
    shortx8 kpre[2], vpre[2];
    float bpre = 0.f;
    auto prefetch = [&](int kbase) {
        #pragma unroll
        for (int c = 0; c < 2; c++) {
            int gk = kbase + kKr[c];
            shortx8 kv = {};
            if (gk < nk) kv = *(const shortx8*)(kh + ((size_t)h * T_TOK + base + gk) * 64 + kSeg[c] * 8);
            kpre[c] = kv;
            int gv = kbase + vKr[c];
            shortx8 vv = {};
            if (gv < nk) vv = *(const shortx8*)(vh + ((size_t)h * T_TOK + base + gv) * 64 + vSeg[c] * 8);
            vpre[c] = vv;
        }
        if (tid < 64) {
            int gk = kbase + tid;
            bpre = (gk < nk) ? (1.0f - mask[base + gk]) * -10000.0f : -30000.0f;
        }
    };
    float mrow[4] = {-3.0e38f, -3.0e38f, -3.0e38f, -3.0e38f};
    float lrow[4] = {0.f, 0.f, 0.f, 0.f};
    floatx4 accO[4] = {};
    short* pbuf = &Ps[wv][0];
    int nkt = (nk + 63) >> 6;
    prefetch(0);
    for (int kt0 = 0; kt0 < nkt; kt0++) {
        __syncthreads();
        #pragma unroll
        for (int c = 0; c < 2; c++) {
            *(shortx8*)&Ks[kKr[c] * 72 + kSeg[c] * 8] = kpre[c];
            bf16* vb = (bf16*)&vpre[c];
            #pragma unroll
            for (int j = 0; j < 8; j++)
                Vs[(vSeg[c] * 8 + j) * 72 + vKr[c]] = *(short*)&vb[j];
        }
        if (tid < 64) bias_s[tid] = bpre;
        if (kt0 + 1 < nkt) prefetch((kt0 + 1) * 64);
        __syncthreads();
        floatx4 s[4];
        #pragma unroll
        for (int nt = 0; nt < 4; nt++) {
            floatx4 accS = {};
            shortx8 k0 = *(const shortx8*)&Ks[(nt * 16 + lr) * 72 + lq * 8];
            shortx8 k1 = *(const shortx8*)&Ks[(nt * 16 + lr) * 72 + 32 + lq * 8];
            accS = __builtin_amdgcn_mfma_f32_16x16x32_bf16(qf[0], k0, accS, 0, 0, 0);
            accS = __builtin_amdgcn_mfma_f32_16x16x32_bf16(qf[1], k1, accS, 0, 0, 0);
            s[nt] = accS;
        }
        float tmax[4] = {-3.0e38f, -3.0e38f, -3.0e38f, -3.0e38f};
        #pragma unroll
        for (int nt = 0; nt < 4; nt++) {
            float bv = bias_s[nt * 16 + lr];
            #pragma unroll
            for (int rg = 0; rg < 4; rg++) {
                float sv = s[nt][rg] * 0.125f + bv;
                s[nt][rg] = sv;
                tmax[rg] = fmaxf(tmax[rg], sv);
            }
        }
        #pragma unroll
        for (int rg = 0; rg < 4; rg++) {
            for (int o = 1; o < 16; o <<= 1) tmax[rg] = fmaxf(tmax[rg], __shfl_xor(tmax[rg], o, 16));
        }
        float fac[4], tsum[4] = {0.f, 0.f, 0.f, 0.f};
        #pragma unroll
        for (int rg = 0; rg < 4; rg++) {
            float mn = fmaxf(mrow[rg], tmax[rg]);
            fac[rg] = __expf(mrow[rg] - mn);
            mrow[rg] = mn;
        }
        #pragma unroll
        for (int nt = 0; nt < 4; nt++) {
            #pragma unroll
            for (int rg = 0; rg < 4; rg++) {
                float e = __expf(s[nt][rg] - mrow[rg]);
                s[nt][rg] = e;
                tsum[rg] += e;
            }
        }
        #pragma unroll
        for (int rg = 0; rg < 4; rg++) {
            for (int o = 1; o < 16; o <<= 1) tsum[rg] += __shfl_xor(tsum[rg], o, 16);
            lrow[rg] = lrow[rg] * fac[rg] + tsum[rg];
        }
        #pragma unroll
        for (int dt = 0; dt < 4; dt++)
            #pragma unroll
            for (int rg = 0; rg < 4; rg++) accO[dt][rg] *= fac[rg];
        #pragma unroll
        for (int nt = 0; nt < 4; nt++) {
            #pragma unroll
            for (int rg = 0; rg < 4; rg++) {
                bf16 pv = f2b(s[nt][rg]);
                pbuf[(lq * 4 + rg) * 72 + nt * 16 + lr] = *(short*)&pv;
            }
        }
        #pragma unroll
        for (int ks = 0; ks < 2; ks++) {
            shortx8 pf = *(const shortx8*)&pbuf[lr * 72 + ks * 32 + lq * 8];
            #pragma unroll
            for (int dt = 0; dt < 4; dt++) {
                shortx8 vf = *(const shortx8*)&Vs[(dt * 16 + lr) * 72 + ks * 32 + lq * 8];
                accO[dt] = __builtin_amdgcn_mfma_f32_16x16x32_bf16(pf, vf, accO[dt], 0, 0, 0);
            }
        }
    }
    float invl[4];
    #pragma unroll
    for (int rg = 0; rg < 4; rg++) invl[rg] = 1.0f / lrow[rg];
    #pragma unroll
    for (int rg = 0; rg < 4; rg++) {
        int qr = q0 + lq * 4 + rg;
        if (qr < nk) {
            bf16* orow = out + (size_t)(base + qr) * C_DIM + h * 64 + lr;
            #pragma unroll
            for (int dt = 0; dt < 4; dt++)
                orow[dt * 16] = f2b(accO[dt][rg] * invl[rg]);
        }
    }
}

// ---------------- output assembly at OUT layers (f32 out) ----------------
__global__ __launch_bounds__(256) void k_output(
    const float* __restrict__ xF, const bf16* __restrict__ lxB,
    const float* __restrict__ fw, const float* __restrict__ fb, float* __restrict__ dst) {
    int b = blockIdx.x;                 // 0..1151
    int s = b / 576, nn = b - s * 576;
    int t = s * NLOC + nn + 1;          // skip token 0
    const float* xr = xF + (size_t)t * C_DIM;
    float sum = 0.f, s2 = 0.f;
    for (int c = threadIdx.x; c < C_DIM; c += 256) { float v = xr[c]; sum += v; s2 += v * v; }
    __shared__ float red[8];
    for (int o = 32; o; o >>= 1) { sum += __shfl_xor(sum, o, 64); s2 += __shfl_xor(s2, o, 64); }
    if ((threadIdx.x & 63) == 0) { red[threadIdx.x >> 6] = sum; red[4 + (threadIdx.x >> 6)] = s2; }
    __syncthreads();
    sum = red[0] + red[1] + red[2] + red[3];
    s2 = red[4] + red[5] + red[6] + red[7];
    float mean = sum * (1.0f / C_DIM);
    float var = s2 * (1.0f / C_DIM) - mean * mean;
    if (var < 0.f) var = 0.f;
    float inv = rsqrtf(var + 1e-6f);
    float* orow = dst + (size_t)b * 1536;
    const bf16* lr = lxB + (size_t)t * C_DIM;
    for (int c = threadIdx.x; c < C_DIM; c += 256) {
        orow[c] = b2f(lr[c]);
        float v = (xr[c] - mean) * inv * fw[c] + fb[c];
        orow[768 + c] = v;
    }
}

// ---------------- camera tokens (layer 11, no final LN) ----------------
__global__ void k_cam(const float* __restrict__ xF, const bf16* __restrict__ lxB,
                      float* __restrict__ dst) {
    for (int idx = threadIdx.x; idx < 2 * 1536; idx += 256) {
        int s = idx / 1536, c = idx - s * 1536;
        int t = s * NLOC;
        float v = (c < 768) ? b2f(lxB[(size_t)t * 768 + c]) : xF[(size_t)t * 768 + (c - 768)];
        dst[idx] = v;
    }
}

extern "C" void kernel_launch(void* const* d_in, const int* in_sizes, int n_in,
                              void* d_out, int out_size, void* d_ws, size_t ws_size,
                              hipStream_t stream) {
    const float* xin  = (const float*)d_in[0];
    const float* rcl  = (const float*)d_in[1];
    const float* rsl  = (const float*)d_in[2];
    const float* rcg  = (const float*)d_in[3];
    const float* rsg  = (const float*)d_in[4];
    const float* kvl  = (const float*)d_in[5];
    const float* kvg  = (const float*)d_in[6];
    const float* cam  = (const float*)d_in[7];
    const float* qkvw = (const float*)d_in[8];
    const float* qkvb = (const float*)d_in[9];
    const float* qnw  = (const float*)d_in[10];
    const float* knw  = (const float*)d_in[11];
    const float* pw   = (const float*)d_in[12];
    const float* pb   = (const float*)d_in[13];
    const float* ls1  = (const float*)d_in[14];
    const float* ls2  = (const float*)d_in[15];
    const float* n1w  = (const float*)d_in[16];
    const float* n1b  = (const float*)d_in[17];
    const float* n2w  = (const float*)d_in[18];
    const float* n2b  = (const float*)d_in[19];
    const float* f1w  = (const float*)d_in[20];
    const float* f1b  = (const float*)d_in[21];
    const float* f2w  = (const float*)d_in[22];
    const float* f2b_ = (const float*)d_in[23];
    const float* fnw  = (const float*)d_in[24];
    const float* fnb  = (const float*)d_in[25];

    char* ws = (char*)d_ws;
    const size_t TC = (size_t)T_TOK * C_DIM;                 // 886,272
    float* xF  = (float*)ws; ws += TC * 4;
    bf16* bufA = (bf16*)ws;  ws += (size_t)T_TOK * 3072 * 2;
    bf16* qhb  = (bf16*)ws;  ws += TC * 2;
    bf16* khb  = (bf16*)ws;  ws += TC * 2;
    bf16* vhb  = (bf16*)ws;  ws += TC * 2;
    bf16* hbuf = (bf16*)ws;  ws += TC * 2;
    bf16* lxB  = (bf16*)ws;  ws += TC * 2;
    float* PP  = (float*)ws; ws += TC * 4 * 2;               // 2 split-K partials
    bf16* wAll = (bf16*)ws;
    size_t usedBase = (size_t)(ws - (char*)d_ws);
    bool bigW = ws_size >= usedBase + 12ull * NWTOT * 2ull;  // +170 MB all-layer weights
    (void)n_in; (void)in_sizes; (void)out_size;

    float* out_b = (float*)d_out;
    const int TC4 = (int)(TC / 4);   // 221568 float4 elements

    k_init<<<(int)((TC + 255) / 256), 256, 0, stream>>>(xin, cam, xF, (int)TC);
    if (bigW)
        k_wconv3<<<dim3(576, 4, 12), 256, 0, stream>>>(qkvw, pw, f1w, f2w, wAll);

    // layers after which a k_fold runs (snapshot or output needs materialized xF)
    auto foldAfter = [](int i) { return i == 2 || i == 4 || i == 5 || i == 8 || i == 10 || i == 11; };

    int outIdx = 0;
    for (int i = 0; i < 12; i++) {
        bool isGlobal = (i & 1);
        bf16* wL;
        if (bigW) {
            wL = wAll + (size_t)i * NWTOT;
        } else {
            k_wconv3<<<dim3(576, 4, 1), 256, 0, stream>>>(
                qkvw + (size_t)i * NQ, pw + (size_t)i * NP,
                f1w + (size_t)i * NF1, f2w + (size_t)i * NF2, wAll);
            wL = wAll;
        }
        // LN1 (folds previous layer's fc2 partials unless a k_fold already ran)
        int ln1Fold = (i > 0 && !foldAfter(i - 1)) ? 1 : 0;
        k_ln<<<T_TOK, 256, 0, stream>>>(xF, PP, PP + TC,
            n1w + (size_t)i * 768, n1b + (size_t)i * 768, hbuf, ln1Fold);
        // QKV gemm (64x64) + fused rms/rope/split, grid 19*36=684
        k_gemmQKV<<<684, 256, 0, stream>>>(hbuf, wL + WQ,
            qkvb + (size_t)i * 2304,
            qnw + (size_t)i * 64, knw + (size_t)i * 64,
            isGlobal ? rcg : rcl, isGlobal ? rsg : rsl, isGlobal ? 1154 : 577,
            qhb, khb, vhb, T_TOK, 768);
        // attention -> hbuf
        if (isGlobal)
            k_attn2<<<dim3(19, 12, 1), 256, 0, stream>>>(qhb, khb, vhb, kvg, hbuf, 1154);
        else
            k_attn2<<<dim3(10, 12, 2), 256, 0, stream>>>(qhb, khb, vhb, kvl, hbuf, 577);
        // proj: split-K x2 -> partial buffers (no atomics), grid 19*12*2=456
        k_gemmT<64, 64, 4><<<456, 256, 0, stream>>>(hbuf, wL + WP,
            pb + (size_t)i * 768, ls1 + (size_t)i * 768, nullptr, PP, T_TOK, 768, 768, 19, 2);
        // LN2 (always folds proj partials into xF)
        k_ln<<<T_TOK, 256, 0, stream>>>(xF, PP, PP + TC,
            n2w + (size_t)i * 768, n2b + (size_t)i * 768, hbuf, 1);
        // fc1 + gelu -> bufA: grid 19*48=912
        k_gemmT<64, 64, 1><<<912, 256, 0, stream>>>(hbuf, wL + WF1,
            f1b + (size_t)i * 3072, nullptr, bufA, nullptr, T_TOK, 3072, 768, 19, 1);
        // fc2: split-K x2 -> partial buffers, grid 19*12*2=456
        k_gemmT<64, 64, 4><<<456, 256, 0, stream>>>(bufA, wL + WF2,
            f2b_ + (size_t)i * 768, ls2 + (size_t)i * 768, nullptr, PP, T_TOK, 768, 3072, 19, 2);

        if (foldAfter(i)) {
            int doCast = (i == 2 || i == 4 || i == 8 || i == 10) ? 1 : 0;
            k_fold<<<(TC4 + 255) / 256, 256, 0, stream>>>(xF, PP, PP + TC, lxB, doCast, TC4);
        }

        if (i == 2 || i == 5 || i == 8 || i == 11) {
            k_output<<<1152, 256, 0, stream>>>(xF, lxB, fnw, fnb, out_b + (size_t)outIdx * OUT_PER);
            if (i == 11)
                k_cam<<<1, 256, 0, stream>>>(xF, lxB, out_b + 4ull * OUT_PER);
            outIdx++;
        }
    }
}